// Round 15
// baseline (325.417 us; speedup 1.0000x reference)
//
#include <hip/hip_runtime.h>

typedef unsigned short u16;
typedef unsigned int u32;
typedef unsigned long long u64;
using short8 = __attribute__((ext_vector_type(8))) short;
using f32x4  = __attribute__((ext_vector_type(4))) float;

constexpr int Bb = 64, Ss = 1000, Dd = 128, Hh = 512;
constexpr int NN = Bb * Ss;           // 64000 nodes
constexpr int NSRC = Ss - 2;          // 998 kNN source nodes per batch

// ---------- helpers ----------
__device__ __forceinline__ float bf2f(u16 h) {
    u32 u = ((u32)h) << 16;
    return __builtin_bit_cast(float, u);
}
__device__ __forceinline__ u16 f2bf(float v) {  // RNE, finite inputs only
    u32 u = __builtin_bit_cast(u32, v);
    u32 r = (u + 0x7FFFu + ((u >> 16) & 1u)) >> 16;
    return (u16)r;
}
__device__ __forceinline__ float4 bf4(ushort4 v) {
    float4 r;
    r.x = bf2f(v.x); r.y = bf2f(v.y); r.z = bf2f(v.z); r.w = bf2f(v.w);
    return r;
}
// async 16B global -> LDS (dest = wave-uniform base + lane*16)
__device__ __forceinline__ void gl_lds16(const void* g, void* l) {
    __builtin_amdgcn_global_load_lds(
        (const __attribute__((address_space(1))) void*)g,
        (__attribute__((address_space(3))) void*)l, 16, 0, 0);
}
// accumulate 8 bf16 (in uint4) * w into a[0..7]
__device__ __forceinline__ void acc8(float (&a)[8], uint4 v, float w) {
    u32 c[4] = {v.x, v.y, v.z, v.w};
#pragma unroll
    for (int k = 0; k < 4; ++k) {
        float lo = __builtin_bit_cast(float, c[k] << 16);
        float hi = __builtin_bit_cast(float, c[k] & 0xFFFF0000u);
        a[2 * k]     += lo * w;
        a[2 * k + 1] += hi * w;
    }
}
// accumulate 2 bf16 (in u32) * w into a[0..1]
__device__ __forceinline__ void acc2(float (&a)[2], u32 v, float w) {
    float lo = __builtin_bit_cast(float, v << 16);
    float hi = __builtin_bit_cast(float, v & 0xFFFF0000u);
    a[0] += lo * w;
    a[1] += hi * w;
}
__device__ __forceinline__ void unp8(float (&a)[8], uint4 v) {
    u32 c[4] = {v.x, v.y, v.z, v.w};
#pragma unroll
    for (int k = 0; k < 4; ++k) {
        a[2 * k]     = __builtin_bit_cast(float, c[k] << 16);
        a[2 * k + 1] = __builtin_bit_cast(float, c[k] & 0xFFFF0000u);
    }
}

__device__ __forceinline__ u64 umin64(u64 a, u64 b) { return a < b ? a : b; }
__device__ __forceinline__ u64 umax64(u64 a, u64 b) { return a < b ? b : a; }

// branchless insert of key v into ascending u64 bd[0..7] (drops the max).
__device__ __forceinline__ void ins8u(u64 (&bd)[8], u64 v) {
#pragma unroll
    for (int k = 7; k >= 1; --k)
        bd[k] = umin64(umax64(v, bd[k - 1]), bd[k]);
    bd[0] = umin64(v, bd[0]);
}

// merge own ascending 8-list with partner lane's (lane^mask): keep the 8
// smallest of the union, sorted (bitonic half-cleaners).
__device__ __forceinline__ void merge8(u64 (&a)[8], int mask) {
    u64 b[8];
#pragma unroll
    for (int k = 0; k < 8; ++k)
        b[k] = __shfl_xor((unsigned long long)a[k], mask);
    u64 m[8];
#pragma unroll
    for (int k = 0; k < 8; ++k) m[k] = umin64(a[k], b[7 - k]);
#pragma unroll
    for (int k = 0; k < 4; ++k) {           // distance 4
        u64 lo = umin64(m[k], m[k + 4]), hi = umax64(m[k], m[k + 4]);
        m[k] = lo; m[k + 4] = hi;
    }
#pragma unroll
    for (int base = 0; base < 8; base += 4)  // distance 2
#pragma unroll
        for (int k = 0; k < 2; ++k) {
            u64 lo = umin64(m[base + k], m[base + k + 2]);
            u64 hi = umax64(m[base + k], m[base + k + 2]);
            m[base + k] = lo; m[base + k + 2] = hi;
        }
#pragma unroll
    for (int base = 0; base < 8; base += 2) { // distance 1
        u64 lo = umin64(m[base], m[base + 1]), hi = umax64(m[base], m[base + 1]);
        m[base] = lo; m[base + 1] = hi;
    }
#pragma unroll
    for (int k = 0; k < 8; ++k) a[k] = m[k];
}

// ---------- 1a) kNN binning: 16x16 grid per batch -> global scratch ----------
__global__ __launch_bounds__(256) void knn_bin_kernel(const float* __restrict__ inputs,
                                                      float2* __restrict__ gsxy,
                                                      u16* __restrict__ gsid,
                                                      int* __restrict__ gcst) {
    __shared__ float px[Ss], py[Ss];
    __shared__ int hist[256];
    __shared__ int cur[256];
    int b = blockIdx.x;
    int tid = threadIdx.x;
    const float* base = inputs + (size_t)b * Ss * 2;
    for (int t = tid; t < Ss; t += 256) { px[t] = base[2 * t]; py[t] = base[2 * t + 1]; }
    hist[tid] = 0;
    __syncthreads();
    for (int t = tid; t < Ss; t += 256) {
        int cx = min(15, (int)(px[t] * 16.0f));
        int cy = min(15, (int)(py[t] * 16.0f));
        atomicAdd(&hist[cy * 16 + cx], 1);
    }
    __syncthreads();
    int cnt = hist[tid];
    for (int s = 1; s < 256; s <<= 1) {
        int u = (tid >= s) ? hist[tid - s] : 0;
        __syncthreads();
        hist[tid] += u;
        __syncthreads();
    }
    int st = hist[tid] - cnt;                // exclusive start
    cur[tid] = st;
    gcst[b * 260 + tid] = st;
    if (tid == 0) gcst[b * 260 + 256] = Ss;
    __syncthreads();
    for (int t = tid; t < Ss; t += 256) {
        float x = px[t], y = py[t];
        int cx = min(15, (int)(x * 16.0f));
        int cy = min(15, (int)(y * 16.0f));
        int p = atomicAdd(&cur[cy * 16 + cx], 1);
        gsxy[b * 1000 + p] = make_float2(x, y);
        gsid[b * 1000 + p] = (u16)t;
    }
}

// ---------- 1b) kNN query: 8-lane cooperative windowed scan ----------
__global__ __launch_bounds__(256) void knn_query_kernel(const float* __restrict__ inputs,
                                                        const float2* __restrict__ gsxy,
                                                        const u16* __restrict__ gsid,
                                                        const int* __restrict__ gcst,
                                                        u16* __restrict__ knn,
                                                        int* __restrict__ indeg) {
    __shared__ float2 sxy[Ss];
    __shared__ u16 sid[Ss];
    __shared__ int cst[257];
    int b = blockIdx.x;
    int tid = threadIdx.x;
    for (int t = tid; t < Ss; t += 256) { sxy[t] = gsxy[b * 1000 + t]; sid[t] = gsid[b * 1000 + t]; }
    for (int t = tid; t < 257; t += 256) cst[t] = gcst[b * 260 + t];
    __syncthreads();

    int sub = tid & 7;                   // lane within group
    int g = tid >> 3;                    // group 0..31
    int i = 2 + blockIdx.y * 32 + g;
    if (i >= Ss) return;

    float x = inputs[(size_t)b * 2000 + 2 * i];
    float y = inputs[(size_t)b * 2000 + 2 * i + 1];
    int cx = min(15, (int)(x * 16.0f));
    int cy = min(15, (int)(y * 16.0f));
    const float INF = __builtin_inff();
    constexpr float h = 0.0625f;

    u64 bd[8];
    int w = 1;
    for (;;) {
#pragma unroll
        for (int k = 0; k < 8; ++k) bd[k] = ~0ULL;
        int x0 = max(0, cx - w), x1 = min(15, cx + w);
        int y0 = max(0, cy - w), y1 = min(15, cy + w);
        for (int cyy = y0; cyy <= y1; ++cyy) {
            int p0 = cst[cyy * 16 + x0];
            int p1 = cst[cyy * 16 + x1 + 1];
            for (int p = p0 + sub; p < p1; p += 8) {
                float2 q = sxy[p];
                int j = sid[p];
                float dx = __fsub_rn(x, q.x);
                float dy = __fsub_rn(y, q.y);
                float d2 = __fadd_rn(__fmul_rn(dx, dx), __fmul_rn(dy, dy));
                float d = __fsqrt_rn(d2);
                u64 key = (((u64)__builtin_bit_cast(u32, d)) << 32) | (u32)j;
                key = (j == i) ? ~0ULL : key;
                ins8u(bd, key);
            }
        }
        merge8(bd, 1); merge8(bd, 2); merge8(bd, 4);   // group-wide 8 smallest
        float d7 = __builtin_bit_cast(float, (u32)(bd[6] >> 32));  // NaN if <7 found
        float bL = (x0 > 0)  ? (x - (float)x0 * h) : INF;
        float bR = (x1 < 15) ? ((float)(x1 + 1) * h - x) : INF;
        float bB = (y0 > 0)  ? (y - (float)y0 * h) : INF;
        float bT = (y1 < 15) ? ((float)(y1 + 1) * h - y) : INF;
        float bound = fminf(fminf(bL, bR), fminf(bB, bT));
        if (d7 <= bound - 2e-6f || w >= 16) break;     // NaN compare -> expand
        ++w;
    }

    if (sub == 0) {
        u16* kp = knn + ((size_t)b * NSRC + (i - 2)) * 7;
#pragma unroll
        for (int k = 0; k < 7; ++k) {
            int j = (int)(u32)bd[k];
            kp[k] = (u16)j;
            if (j >= 2) atomicAdd(&indeg[b * Ss + j], 1);
        }
    }
}

// ---------- 3) coalesced scan: phase 1 (+ fused dinv) ----------
__global__ __launch_bounds__(1024) void scan1_kernel(const int* __restrict__ indeg,
                                                     int* __restrict__ offs,
                                                     int* __restrict__ bsum,
                                                     float* __restrict__ dinv) {
    __shared__ int sh[1024];
    int t = threadIdx.x;
    int idx = blockIdx.x * 1024 + t;
    int v = (idx < NN) ? indeg[idx] : 0;
    sh[t] = v;
    __syncthreads();
    for (int off = 1; off < 1024; off <<= 1) {
        int u = (t >= off) ? sh[t - off] : 0;
        __syncthreads();
        sh[t] += u;
        __syncthreads();
    }
    if (idx < NN) {
        offs[idx] = sh[t] - v;            // exclusive prefix
        int ii = idx % Ss;
        float deg = (ii == 0) ? 1.0f : (ii == 1) ? (float)(Ss - 1) : (float)(v + 2);
        dinv[idx] = 1.0f / __fsqrt_rn(deg);
    }
    if (t == 1023) bsum[blockIdx.x] = sh[1023];
}

// ---------- scan phase 2: each block computes its own prefix from raw bsum ----------
__global__ __launch_bounds__(1024) void scan3_kernel(int* __restrict__ offs,
                                                     const int* __restrict__ bsum) {
    __shared__ int spre, stot;
    int t = threadIdx.x;
    if (t < 64) {
        int v = (t < 63) ? bsum[t] : 0;
        int pre = (t < (int)blockIdx.x) ? v : 0;
        int tot = v;
#pragma unroll
        for (int m = 1; m < 64; m <<= 1) {
            pre += __shfl_xor(pre, m);
            tot += __shfl_xor(tot, m);
        }
        if (t == 0) { spre = pre; stot = tot; }
    }
    __syncthreads();
    int idx = blockIdx.x * 1024 + t;
    if (idx < NN) offs[idx] += spre;
    if (idx == 0) offs[NN] = stot;
}

// ---------- 4) scatter reverse adjacency ----------
__global__ __launch_bounds__(256) void fill_rev_kernel(const u16* __restrict__ knn,
                                                       const int* __restrict__ offs,
                                                       int* __restrict__ cursor,
                                                       u16* __restrict__ rev) {
    if (threadIdx.x >= 250) return;
    int b = blockIdx.x;
    int i = 2 + blockIdx.y * 250 + threadIdx.x;
    if (i >= Ss) return;
    const u16* kp = knn + ((size_t)b * NSRC + (i - 2)) * 7;
#pragma unroll
    for (int k = 0; k < 7; ++k) {
        int d = kp[k];
        if (d >= 2) {
            int n = b * Ss + d;
            int p = atomicAdd(&cursor[n], 1);
            rev[offs[n] + p] = (u16)i;
        }
    }
}

// ---------- 5) merged prep: transp W1, transp W2, fold layer-0 weights ----------
__global__ __launch_bounds__(256) void prep_kernel(const float* __restrict__ Wc,
                                                   const float* __restrict__ bc,
                                                   const float* __restrict__ Ws,
                                                   const float* __restrict__ bs,
                                                   const float* __restrict__ W0,
                                                   const float* __restrict__ W1,
                                                   const float* __restrict__ W2,
                                                   float* __restrict__ A,
                                                   u16* __restrict__ wt1,
                                                   u16* __restrict__ wt2) {
    int bid = blockIdx.x;
    int tid = threadIdx.x;
    if (bid < 1024) {                       // transp W1: [512][512] -> wt1[c][r]
        int gid = bid * 256 + tid;
        int r = gid >> 9, c = gid & 511;
        wt1[(size_t)c * 512 + r] = f2bf(W1[gid]);
    } else if (bid < 1024 + 256) {          // transp W2: [512][128] -> wt2[c][r]
        int gid = (bid - 1024) * 256 + tid;
        int r = gid >> 7, c = gid & 127;
        wt2[(size_t)c * 512 + r] = f2bf(W2[gid]);
    } else {                                // fuse0: A = [Wc0;Wc1;Ws;(bc+bs)] @ W0
        int h = (bid - 1280) * 256 + tid;
        float a0 = 0.f, a1 = 0.f, a2 = 0.f, a3 = 0.f;
        for (int c = 0; c < Dd; ++c) {
            float w = W0[c * Hh + h];
            a0 += Wc[c] * w;
            a1 += Wc[Dd + c] * w;
            a2 += Ws[c] * w;
            a3 += (bc[c] + bs[c]) * w;
        }
        A[h] = a0; A[Hh + h] = a1; A[2 * Hh + h] = a2; A[3 * Hh + h] = a3;
    }
}

// ---------- 5b) layer-0 e-space aggregation (rank-4): ve[n] = agg(e)[n] ----------
__global__ __launch_bounds__(1024) void agg_e_kernel(const float* __restrict__ inputs,
                                                     const float* __restrict__ scor,
                                                     const float* __restrict__ dinv,
                                                     const int* __restrict__ offs,
                                                     const int* __restrict__ indeg,
                                                     const u16* __restrict__ rev,
                                                     float4* __restrict__ ve) {
    __shared__ float se0[Ss], se1[Ss], se2[Ss], sdv[Ss];
    __shared__ float4 depw[16];
    int b = blockIdx.x;
    int tid = threadIdx.x;
    int nb = b * Ss;
    const float* base = inputs + (size_t)nb * 2;
    for (int t = tid; t < Ss; t += 1024) {
        se0[t] = base[2 * t];
        se1[t] = base[2 * t + 1];
        se2[t] = scor[nb + t];
        sdv[t] = dinv[nb + t];
    }
    __syncthreads();

    float4 dep = {0.f, 0.f, 0.f, 0.f};
    for (int r = tid; r < Ss; r += 1024) {
        if (r >= 2) {
            float w = sdv[r];
            dep.x += se0[r] * w; dep.y += se1[r] * w;
            dep.z += se2[r] * w; dep.w += w;
        }
    }
#pragma unroll
    for (int m = 1; m < 64; m <<= 1) {
        dep.x += __shfl_xor(dep.x, m);
        dep.y += __shfl_xor(dep.y, m);
        dep.z += __shfl_xor(dep.z, m);
        dep.w += __shfl_xor(dep.w, m);
    }
    if ((tid & 63) == 0) depw[tid >> 6] = dep;
    __syncthreads();

    int i = tid;
    if (i >= Ss) return;
    float dn = sdv[i], sn = dn * dn;
    float4 acc = {0.f, 0.f, 0.f, 0.f};
    if (i >= 2) {
        int n = nb + i;
        int cnt = indeg[n], o = offs[n];
        float w0 = sdv[0];                 // == 1.0
        acc.x = se0[0] * w0; acc.y = se1[0] * w0;
        acc.z = se2[0] * w0; acc.w = w0;   // 0 -> i edge
        for (int e = 0; e < cnt; ++e) {
            int s = rev[o + e];
            float w = sdv[s];
            acc.x += se0[s] * w; acc.y += se1[s] * w;
            acc.z += se2[s] * w; acc.w += w;
        }
    } else if (i == 1) {
        float4 t = {0.f, 0.f, 0.f, 0.f};
#pragma unroll
        for (int k = 0; k < 16; ++k) {
            t.x += depw[k].x; t.y += depw[k].y;
            t.z += depw[k].z; t.w += depw[k].w;
        }
        acc = t;
    }
    float4 v;
    v.x = acc.x * dn + se0[i] * sn;
    v.y = acc.y * dn + se1[i] * sn;
    v.z = acc.z * dn + se2[i] * sn;
    v.w = acc.w * dn + sn;                 // e.w == 1
    ve[nb + i] = v;
}

// ---------- 5c) expand + sx partials: X[n,h]=relu(ve.A+b0); sxp[b][g][h] ----------
__global__ __launch_bounds__(256) void expand512p_kernel(const float4* __restrict__ ve,
                                                         const float* __restrict__ dinv,
                                                         const float* __restrict__ A,
                                                         const float* __restrict__ bias,
                                                         u16* __restrict__ X,
                                                         float* __restrict__ sxp) {
    __shared__ float4 sve[250];
    __shared__ float  sdv[250];
    __shared__ float  sred[8][256];
    int bx = blockIdx.x;               // 0..7
    int g = bx >> 1, cg = bx & 1;      // node-group 0..3, channel half 0..1
    int b = blockIdx.y;
    int n0 = g * 250;
    int nb = b * Ss;
    int tid = threadIdx.x;
    int c32 = tid & 31, slice = tid >> 5;     // 8 node-slices
    int ch = cg * 256 + c32 * 8;
    for (int t = tid; t < 250; t += 256) {
        sve[t] = ve[nb + n0 + t];
        sdv[t] = dinv[nb + n0 + t];
    }
    __syncthreads();

    float A0[8], A1[8], A2[8], A3[8], BZ[8];
#pragma unroll
    for (int j = 0; j < 8; ++j) {
        A0[j] = A[ch + j];
        A1[j] = A[Hh + ch + j];
        A2[j] = A[2 * Hh + ch + j];
        A3[j] = A[3 * Hh + ch + j];
        BZ[j] = bias[ch + j];
    }
    float acc[8] = {};
    for (int t = slice; t < 250; t += 8) {
        int n = n0 + t;
        float4 v = sve[t];
        float dw = (n >= 2) ? sdv[t] : 0.f;
        u32 ow[4];
#pragma unroll
        for (int j = 0; j < 4; ++j) {
            float z0 = fmaxf(v.x * A0[2 * j]     + v.y * A1[2 * j]     + v.z * A2[2 * j]     + v.w * A3[2 * j]     + BZ[2 * j],     0.f);
            float z1 = fmaxf(v.x * A0[2 * j + 1] + v.y * A1[2 * j + 1] + v.z * A2[2 * j + 1] + v.w * A3[2 * j + 1] + BZ[2 * j + 1], 0.f);
            u16 h0 = f2bf(z0), h1 = f2bf(z1);
            ow[j] = (u32)h0 | ((u32)h1 << 16);
            acc[2 * j]     += dw * bf2f(h0);
            acc[2 * j + 1] += dw * bf2f(h1);
        }
        uint4 o = {ow[0], ow[1], ow[2], ow[3]};
        *(uint4*)(X + (size_t)(nb + n) * Hh + ch) = o;
    }
#pragma unroll
    for (int j = 0; j < 8; ++j) sred[slice][c32 * 8 + j] = acc[j];
    __syncthreads();
    if (slice == 0) {
#pragma unroll
        for (int j = 0; j < 8; ++j) {
            float s = 0.f;
#pragma unroll
            for (int sl = 0; sl < 8; ++sl) s += sred[sl][c32 * 8 + j];
            sxp[((size_t)b * 4 + g) * Hh + ch + j] = s;
        }
    }
}

// ---------- 5d) k-split dep matmul ----------
__global__ __launch_bounds__(512) void sxk_kernel(const float* __restrict__ sxp,
                                                  const float* __restrict__ W1,
                                                  float* __restrict__ depp) {
    __shared__ float sx[64];
    int kc = blockIdx.x;               // k-chunk 0..7
    int b  = blockIdx.y;
    int t  = threadIdx.x;
    if (t < 64) {
        int k = kc * 64 + t;
        float s = 0.f;
#pragma unroll
        for (int g = 0; g < 4; ++g) s += sxp[((size_t)b * 4 + g) * Hh + k];
        sx[t] = s;
    }
    __syncthreads();
    float a = 0.f;
#pragma unroll 8
    for (int kk = 0; kk < 64; ++kk)
        a += sx[kk] * W1[(size_t)(kc * 64 + kk) * Hh + t];
    depp[((size_t)kc * Bb + b) * Hh + t] = a;
}

// ---------- 5e) reduce 8 k-chunk partials -> flat depf[64][512] ----------
__global__ __launch_bounds__(512) void sxred_kernel(const float* __restrict__ depp,
                                                    float* __restrict__ depf) {
    int b = blockIdx.x, t = threadIdx.x;
    float s = 0.f;
#pragma unroll
    for (int kc = 0; kc < 8; ++kc)
        s += depp[((size_t)kc * Bb + b) * Hh + t];
    depf[(size_t)b * Hh + t] = s;
}

// ---------- 7) MFMA GEMM: Y(bf16) = A(bf16) @ W(bf16)^T ----------
// 256x128 tile, 8 waves (512 thr). nxi inner col-tiles per block halve the
// grid (512 blocks <= 768 resident slots at 48KB LDS -> zero tail round).
// A restaged per inner tile (L2-hit; HBM fetch unchanged). XCD-grouped grid;
// global_load_lds w16 with pre-swizzled global source.
__global__ __launch_bounds__(512) void gemm_kernel(const u16* __restrict__ A,
                                                   const u16* __restrict__ W,
                                                   u16* __restrict__ Y,
                                                   int K, int Ncols,
                                                   int nyb, int nxb, int nxi) {
    __shared__ __align__(16) u16 lA[256][64];
    __shared__ __align__(16) u16 lW[128][64];

    int grp = blockIdx.x / (8 * nxb);
    int rem = blockIdx.x - grp * (8 * nxb);
    int xcd = rem & 7;
    int xb  = rem >> 3;
    int yb  = grp * 8 + xcd;
    if (yb >= nyb) return;

    int row0 = yb * 256;
    int tid = threadIdx.x;
    int lane = tid & 63, wid = tid >> 6;        // 8 waves
    int wm = (wid >> 1) * 64, wn = (wid & 1) * 64;   // 4x2 wave grid
    int lanelo = lane & 15, quad = lane >> 4;

    int lrow = lane >> 3;               // row within 8-row chunk
    int lslot = lane & 7;               // 16B slot within row

    for (int xi = 0; xi < nxi; ++xi) {
        int col0 = (xb + xi * nxb) * 128;
        f32x4 acc[4][4] = {};

        for (int k0 = 0; k0 < K; k0 += 64) {
#pragma unroll
            for (int t = 0; t < 4; ++t) {               // A: 32 chunks over 8 waves
                int chunk = t * 8 + wid;                // 0..31
                int row = chunk * 8 + lrow;             // 0..255
                int sc = lslot ^ (row & 7);             // pre-swizzled global slot
                gl_lds16(A + (size_t)(row0 + row) * K + k0 + sc * 8, &lA[chunk * 8][0]);
            }
#pragma unroll
            for (int t = 0; t < 2; ++t) {               // W: 16 chunks over 8 waves
                int chunk = t * 8 + wid;                // 0..15
                int row = chunk * 8 + lrow;             // 0..127
                int sc = lslot ^ (row & 7);
                gl_lds16(W + (size_t)(col0 + row) * K + k0 + sc * 8, &lW[chunk * 8][0]);
            }
            __syncthreads();

#pragma unroll
            for (int kk = 0; kk < 64; kk += 32) {
                short8 af[4], bw[4];
                int cbb = (kk >> 3) + quad;
#pragma unroll
                for (int mt = 0; mt < 4; ++mt) {
                    int r = wm + mt * 16 + lanelo;
                    af[mt] = *(const short8*)&lA[r][((cbb ^ (r & 7))) * 8];
                }
#pragma unroll
                for (int nt = 0; nt < 4; ++nt) {
                    int r = wn + nt * 16 + lanelo;
                    bw[nt] = *(const short8*)&lW[r][((cbb ^ (r & 7))) * 8];
                }
#pragma unroll
                for (int mt = 0; mt < 4; ++mt)
#pragma unroll
                    for (int nt = 0; nt < 4; ++nt)
                        acc[mt][nt] = __builtin_amdgcn_mfma_f32_16x16x32_bf16(
                            af[mt], bw[nt], acc[mt][nt], 0, 0, 0);
            }
            __syncthreads();
        }

#pragma unroll
        for (int mt = 0; mt < 4; ++mt)
#pragma unroll
            for (int nt = 0; nt < 4; ++nt)
#pragma unroll
                for (int r = 0; r < 4; ++r) {
                    int row = row0 + wm + mt * 16 + quad * 4 + r;
                    int col = col0 + wn + nt * 16 + lanelo;
                    Y[(size_t)row * Ncols + col] = f2bf(acc[mt][nt][r]);
                }
    }
}

// ---------- 7b) depot-1 partial sums (layer 2 only) ----------
__global__ __launch_bounds__(1024) void dep1_kernel(const u16* __restrict__ y,
                                                    const float* __restrict__ dinv,
                                                    float* __restrict__ dq,
                                                    int M) {
    int b = blockIdx.x;
    int qq = blockIdx.y;                 // quarter 0..3
    int co = blockIdx.z * 128;
    int tid = threadIdx.x;
    int c4 = tid & 31;
    int es = tid >> 5;
    int j0 = 2 + qq * 250;
    int j1 = j0 + 250; if (j1 > Ss) j1 = Ss;
    const u16* yb = y + (size_t)b * Ss * M + co + c4 * 4;
    const float* dv = dinv + b * Ss;
    float a0 = 0.f, a1 = 0.f, a2 = 0.f, a3 = 0.f;
    for (int j = j0 + es; j < j1; j += 32) {
        float w = dv[j];
        float4 u = bf4(*(const ushort4*)(yb + (size_t)j * M));
        a0 += u.x * w; a1 += u.y * w; a2 += u.z * w; a3 += u.w * w;
    }
    __shared__ float4 red[1024];
    float4 mv; mv.x = a0; mv.y = a1; mv.z = a2; mv.w = a3;
    red[tid] = mv;
    __syncthreads();
#pragma unroll
    for (int s = 16; s > 0; s >>= 1) {
        if (es < s) {
            float4 o = red[tid + (s << 5)];
            float4 m = red[tid];
            m.x += o.x; m.y += o.y; m.z += o.z; m.w += o.w;
            red[tid] = m;
        }
        __syncthreads();
    }
    if (es == 0)
        *(float4*)(dq + ((size_t)qq * Bb + b) * M + co + c4 * 4) = red[c4];
}

// ---------- 8) wave-per-node aggregation M=512, XCD-pinned batch mapping ----------
__global__ __launch_bounds__(256) void aggw512_kernel(const u16* __restrict__ y,
                                                      const float* __restrict__ dinv,
                                                      const int* __restrict__ offs,
                                                      const int* __restrict__ indeg,
                                                      const u16* __restrict__ rev,
                                                      const float* __restrict__ bias,
                                                      const float* __restrict__ dep1,
                                                      u16* __restrict__ oX) {
    int tid = threadIdx.x;
    int wv = tid >> 6, lane = tid & 63;
    int bx = blockIdx.x;                  // 0..15999
    int b = (bx & 7) + 8 * (bx / 2000);   // batch, pinned per XCD
    int i = ((bx >> 3) % 250) * 4 + wv;   // node index within batch
    int nb = b * Ss;
    int n = nb + i;
    const u16* yB = y + (size_t)nb * 512 + lane * 8;

    float acc[8] = {};
    if (i >= 2) {
        int cnt = indeg[n], o = offs[n];
        int rv = 0; float rw = 0.f;
        if (lane < 16 && lane < cnt) { rv = rev[o + lane]; rw = dinv[nb + rv]; }
        float w0 = dinv[nb];              // == 1.0 (deg of node 0)
        uint4 v0 = *(const uint4*)yB;     // 0 -> i edge
        acc8(acc, v0, w0);
        int cl = cnt < 16 ? cnt : 16;
        int e = 0;
        for (; e + 4 <= cl; e += 4) {
            int   s0 = __shfl(rv, e),     s1 = __shfl(rv, e + 1);
            int   s2 = __shfl(rv, e + 2), s3 = __shfl(rv, e + 3);
            float w_0 = __shfl(rw, e),     w_1 = __shfl(rw, e + 1);
            float w_2 = __shfl(rw, e + 2), w_3 = __shfl(rw, e + 3);
            uint4 u0 = *(const uint4*)(yB + (size_t)s0 * 512);
            uint4 u1 = *(const uint4*)(yB + (size_t)s1 * 512);
            uint4 u2 = *(const uint4*)(yB + (size_t)s2 * 512);
            uint4 u3 = *(const uint4*)(yB + (size_t)s3 * 512);
            acc8(acc, u0, w_0); acc8(acc, u1, w_1);
            acc8(acc, u2, w_2); acc8(acc, u3, w_3);
        }
        for (; e < cl; ++e) {
            int s = __shfl(rv, e); float ww = __shfl(rw, e);
            uint4 u = *(const uint4*)(yB + (size_t)s * 512);
            acc8(acc, u, ww);
        }
        for (; e < cnt; ++e) {            // rare tail (indeg > 16)
            int s = rev[o + e]; float ww = dinv[nb + s];
            uint4 u = *(const uint4*)(yB + (size_t)s * 512);
            acc8(acc, u, ww);
        }
    } else if (i == 1) {
        const float* dp = dep1 + (size_t)b * 512 + lane * 8;
        float4 v0 = *(const float4*)dp;
        float4 v1 = *(const float4*)(dp + 4);
        acc[0] = v0.x; acc[1] = v0.y; acc[2] = v0.z; acc[3] = v0.w;
        acc[4] = v1.x; acc[5] = v1.y; acc[6] = v1.z; acc[7] = v1.w;
    }
    float dn = dinv[n], sn = dn * dn;
    float s8[8];
    unp8(s8, *(const uint4*)(yB + (size_t)i * 512));
    float4 bl = *(const float4*)(bias + lane * 8);
    float4 bh = *(const float4*)(bias + lane * 8 + 4);
    float bz[8] = {bl.x, bl.y, bl.z, bl.w, bh.x, bh.y, bh.z, bh.w};
    u32 ow[4];
#pragma unroll
    for (int k = 0; k < 4; ++k) {
        float z0 = acc[2 * k]     * dn + s8[2 * k]     * sn + bz[2 * k];
        float z1 = acc[2 * k + 1] * dn + s8[2 * k + 1] * sn + bz[2 * k + 1];
        ow[k] = (u32)f2bf(fmaxf(z0, 0.f)) | ((u32)f2bf(fmaxf(z1, 0.f)) << 16);
    }
    uint4 ov = {ow[0], ow[1], ow[2], ow[3]};
    *(uint4*)(oX + (size_t)n * 512 + lane * 8) = ov;
}

// ---------- 9) wave-per-node final aggregation M=128, fp32 out ----------
__global__ __launch_bounds__(256) void aggwf128_kernel(const u16* __restrict__ y,
                                                       const float* __restrict__ dinv,
                                                       const int* __restrict__ offs,
                                                       const int* __restrict__ indeg,
                                                       const u16* __restrict__ rev,
                                                       const float* __restrict__ bias,
                                                       const float* __restrict__ dep1,
                                                       float* __restrict__ out) {
    int tid = threadIdx.x;
    int wv = tid >> 6, lane = tid & 63;
    int bx = blockIdx.x;                  // 0..15999
    int b = (bx & 7) + 8 * (bx / 2000);   // batch, pinned per XCD
    int i = ((bx >> 3) % 250) * 4 + wv;   // node index within batch
    int nb = b * Ss;
    int n = nb + i;
    const u16* yB = y + (size_t)nb * 128 + lane * 2;

    float acc[2] = {};
    if (i >= 2) {
        int cnt = indeg[n], o = offs[n];
        int rv = 0; float rw = 0.f;
        if (lane < 16 && lane < cnt) { rv = rev[o + lane]; rw = dinv[nb + rv]; }
        float w0 = dinv[nb];              // == 1.0
        acc2(acc, *(const u32*)yB, w0);   // 0 -> i edge
        int cl = cnt < 16 ? cnt : 16;
        int e = 0;
        for (; e + 4 <= cl; e += 4) {
            int   s0 = __shfl(rv, e),     s1 = __shfl(rv, e + 1);
            int   s2 = __shfl(rv, e + 2), s3 = __shfl(rv, e + 3);
            float w_0 = __shfl(rw, e),     w_1 = __shfl(rw, e + 1);
            float w_2 = __shfl(rw, e + 2), w_3 = __shfl(rw, e + 3);
            u32 u0 = *(const u32*)(yB + (size_t)s0 * 128);
            u32 u1 = *(const u32*)(yB + (size_t)s1 * 128);
            u32 u2 = *(const u32*)(yB + (size_t)s2 * 128);
            u32 u3 = *(const u32*)(yB + (size_t)s3 * 128);
            acc2(acc, u0, w_0); acc2(acc, u1, w_1);
            acc2(acc, u2, w_2); acc2(acc, u3, w_3);
        }
        for (; e < cl; ++e) {
            int s = __shfl(rv, e); float ww = __shfl(rw, e);
            acc2(acc, *(const u32*)(yB + (size_t)s * 128), ww);
        }
        for (; e < cnt; ++e) {            // rare tail (indeg > 16)
            int s = rev[o + e]; float ww = dinv[nb + s];
            acc2(acc, *(const u32*)(yB + (size_t)s * 128), ww);
        }
    } else if (i == 1) {
        const float* dp = dep1 + (size_t)b * 128 + lane * 2;
#pragma unroll
        for (int qq = 0; qq < 4; ++qq) {
            float2 v = *(const float2*)(dp + (size_t)qq * Bb * 128);
            acc[0] += v.x; acc[1] += v.y;
        }
    }
    float dn = dinv[n], sn = dn * dn;
    u32 sv = *(const u32*)(yB + (size_t)i * 128);
    float s0 = __builtin_bit_cast(float, sv << 16);
    float s1 = __builtin_bit_cast(float, sv & 0xFFFF0000u);
    float2 bz = *(const float2*)(bias + lane * 2);
    float2 z;
    z.x = acc[0] * dn + s0 * sn + bz.x;
    z.y = acc[1] * dn + s1 * sn + bz.y;
    *(float2*)(out + (size_t)n * 128 + lane * 2) = z;
}

// ---------- workspace layout (bytes) ----------
constexpr size_t O_INDEG  = 0;                       // 256000
constexpr size_t O_CURSOR = 256000;                  // 256000
constexpr size_t O_OFFS   = 512000;                  // 256016
constexpr size_t O_DINV   = 768256;                  // 256000
constexpr size_t O_KNN    = 1024256;                 // 893824
constexpr size_t O_REV    = 1918080;                 // 893824
constexpr size_t O_AMAT   = 2811904;                 // 8192
constexpr size_t O_WT1    = 2942976;                 // 524288
constexpr size_t O_WT2    = 3467264;                 // 131072
constexpr size_t O_X      = 3598336;                 // 65536000 (bf16 acts)
constexpr size_t O_Y      = 69134336;                // 65536000 (bf16 y; ve fp32 early)
constexpr size_t O_SXP    = 134670336;               // 64*4*512*4 = 524288 (sx partials)
constexpr size_t O_DEPF   = 135194624;               // 64*512*4 = 131072 (flat dep L1;
                                                     //  aliased by L2 quarters later)
constexpr size_t O_BSUM   = 135325696;               // 256
// kNN scratch aliased into O_X (consumed before expand writes xbf):
constexpr size_t O_GSXY   = O_X;                     // 64*1000*8 = 512000
constexpr size_t O_GSID   = O_X + 512000;            // 64*1000*2 = 128000
constexpr size_t O_GCST   = O_X + 640000;            // 64*260*4 = 66560
// ve (64000 float4 = 1.024 MB) aliased into O_Y (consumed before gemm1 writes ybf)
constexpr size_t O_VE     = O_Y;
// depp (8*64*512*4 = 1 MB) aliased into O_Y+4MB (live only sxk->sxred, pre-gemm1)
constexpr size_t O_DEPP   = O_Y + 4194304;

extern "C" void kernel_launch(void* const* d_in, const int* in_sizes, int n_in,
                              void* d_out, int out_size, void* d_ws, size_t ws_size,
                              hipStream_t stream) {
    const float* inputs = (const float*)d_in[0];
    const float* scor   = (const float*)d_in[1];
    const float* Wc     = (const float*)d_in[2];
    const float* bc     = (const float*)d_in[3];
    const float* Ws     = (const float*)d_in[4];
    const float* bs     = (const float*)d_in[5];
    const float* W0     = (const float*)d_in[6];
    const float* b0     = (const float*)d_in[7];
    const float* W1     = (const float*)d_in[8];
    const float* b1     = (const float*)d_in[9];
    const float* W2     = (const float*)d_in[10];
    const float* b2     = (const float*)d_in[11];

    char* w = (char*)d_ws;
    int*    indeg  = (int*)(w + O_INDEG);
    int*    cursor = (int*)(w + O_CURSOR);
    int*    offs   = (int*)(w + O_OFFS);
    float*  dinv   = (float*)(w + O_DINV);
    u16*    knn    = (u16*)(w + O_KNN);
    u16*    rev    = (u16*)(w + O_REV);
    float*  amat   = (float*)(w + O_AMAT);
    u16*    wt1    = (u16*)(w + O_WT1);
    u16*    wt2    = (u16*)(w + O_WT2);
    u16*    xbf    = (u16*)(w + O_X);
    u16*    ybf    = (u16*)(w + O_Y);
    float*  sxp    = (float*)(w + O_SXP);
    float*  depf   = (float*)(w + O_DEPF);
    float*  depp   = (float*)(w + O_DEPP);
    int*    bsum   = (int*)(w + O_BSUM);
    float2* gsxy   = (float2*)(w + O_GSXY);
    u16*    gsid   = (u16*)(w + O_GSID);
    int*    gcst   = (int*)(w + O_GCST);
    float4* ve     = (float4*)(w + O_VE);

    hipMemsetAsync(w + O_INDEG, 0, 512000, stream);  // indeg + cursor

    knn_bin_kernel<<<Bb, 256, 0, stream>>>(inputs, gsxy, gsid, gcst);
    knn_query_kernel<<<dim3(Bb, 32), 256, 0, stream>>>(inputs, gsxy, gsid, gcst, knn, indeg);
    scan1_kernel<<<63, 1024, 0, stream>>>(indeg, offs, bsum, dinv);
    scan3_kernel<<<63, 1024, 0, stream>>>(offs, bsum);
    fill_rev_kernel<<<dim3(Bb, 4), 256, 0, stream>>>(knn, offs, cursor, rev);

    prep_kernel<<<1282, 256, 0, stream>>>(Wc, bc, Ws, bs, W0, W1, W2, amat, wt1, wt2);

    // layer 0: rank-4 e-space aggregation + fused expand with sx partials
    agg_e_kernel<<<Bb, 1024, 0, stream>>>(inputs, scor, dinv, offs, indeg, rev, ve);
    expand512p_kernel<<<dim3(8, Bb), 256, 0, stream>>>(ve, dinv, amat, b0, xbf, sxp);
    sxk_kernel<<<dim3(8, Bb), 512, 0, stream>>>(sxp, W1, depp);    // k-split dep matmul
    sxred_kernel<<<Bb, 512, 0, stream>>>(depp, depf);              // -> flat dep1a
    // layer 1: [N,512] @ [512,512]; 250 row panels, 2 col pairs x 2 inner tiles
    gemm_kernel<<<32 * 8 * 2, 512, 0, stream>>>(xbf, wt1, ybf, Hh, Hh, 250, 2, 2);
    aggw512_kernel<<<NN / 4, 256, 0, stream>>>(ybf, dinv, offs, indeg, rev, b1, depf, xbf);
    // layer 2: [N,512] @ [512,128]; 250 row panels, 1 col block
    gemm_kernel<<<32 * 8, 512, 0, stream>>>(xbf, wt2, ybf, Hh, Dd, 250, 1, 1);
    dep1_kernel<<<dim3(Bb, 4, 1), 1024, 0, stream>>>(ybf, dinv, depf, Dd);   // quarters, aliased
    aggwf128_kernel<<<NN / 4, 256, 0, stream>>>(ybf, dinv, offs, indeg, rev, b2, depf, (float*)d_out);
}

// Round 16
// 308.485 us; speedup vs baseline: 1.0549x; 1.0549x over previous
//
#include <hip/hip_runtime.h>

typedef unsigned short u16;
typedef unsigned int u32;
typedef unsigned long long u64;
using short8 = __attribute__((ext_vector_type(8))) short;
using f32x4  = __attribute__((ext_vector_type(4))) float;

constexpr int Bb = 64, Ss = 1000, Dd = 128, Hh = 512;
constexpr int NN = Bb * Ss;           // 64000 nodes
constexpr int NSRC = Ss - 2;          // 998 kNN source nodes per batch

// ---------- helpers ----------
__device__ __forceinline__ float bf2f(u16 h) {
    u32 u = ((u32)h) << 16;
    return __builtin_bit_cast(float, u);
}
__device__ __forceinline__ u16 f2bf(float v) {  // RNE, finite inputs only
    u32 u = __builtin_bit_cast(u32, v);
    u32 r = (u + 0x7FFFu + ((u >> 16) & 1u)) >> 16;
    return (u16)r;
}
__device__ __forceinline__ float4 bf4(ushort4 v) {
    float4 r;
    r.x = bf2f(v.x); r.y = bf2f(v.y); r.z = bf2f(v.z); r.w = bf2f(v.w);
    return r;
}
// async 16B global -> LDS (dest = wave-uniform base + lane*16)
__device__ __forceinline__ void gl_lds16(const void* g, void* l) {
    __builtin_amdgcn_global_load_lds(
        (const __attribute__((address_space(1))) void*)g,
        (__attribute__((address_space(3))) void*)l, 16, 0, 0);
}
// accumulate 8 bf16 (in uint4) * w into a[0..7]
__device__ __forceinline__ void acc8(float (&a)[8], uint4 v, float w) {
    u32 c[4] = {v.x, v.y, v.z, v.w};
#pragma unroll
    for (int k = 0; k < 4; ++k) {
        float lo = __builtin_bit_cast(float, c[k] << 16);
        float hi = __builtin_bit_cast(float, c[k] & 0xFFFF0000u);
        a[2 * k]     += lo * w;
        a[2 * k + 1] += hi * w;
    }
}
// accumulate 2 bf16 (in u32) * w into a[0..1]
__device__ __forceinline__ void acc2(float (&a)[2], u32 v, float w) {
    float lo = __builtin_bit_cast(float, v << 16);
    float hi = __builtin_bit_cast(float, v & 0xFFFF0000u);
    a[0] += lo * w;
    a[1] += hi * w;
}
__device__ __forceinline__ void unp8(float (&a)[8], uint4 v) {
    u32 c[4] = {v.x, v.y, v.z, v.w};
#pragma unroll
    for (int k = 0; k < 4; ++k) {
        a[2 * k]     = __builtin_bit_cast(float, c[k] << 16);
        a[2 * k + 1] = __builtin_bit_cast(float, c[k] & 0xFFFF0000u);
    }
}

__device__ __forceinline__ u64 umin64(u64 a, u64 b) { return a < b ? a : b; }
__device__ __forceinline__ u64 umax64(u64 a, u64 b) { return a < b ? b : a; }

// branchless insert of key v into ascending u64 bd[0..7] (drops the max).
__device__ __forceinline__ void ins8u(u64 (&bd)[8], u64 v) {
#pragma unroll
    for (int k = 7; k >= 1; --k)
        bd[k] = umin64(umax64(v, bd[k - 1]), bd[k]);
    bd[0] = umin64(v, bd[0]);
}

// merge own ascending 8-list with partner lane's (lane^mask): keep the 8
// smallest of the union, sorted (bitonic half-cleaners).
__device__ __forceinline__ void merge8(u64 (&a)[8], int mask) {
    u64 b[8];
#pragma unroll
    for (int k = 0; k < 8; ++k)
        b[k] = __shfl_xor((unsigned long long)a[k], mask);
    u64 m[8];
#pragma unroll
    for (int k = 0; k < 8; ++k) m[k] = umin64(a[k], b[7 - k]);
#pragma unroll
    for (int k = 0; k < 4; ++k) {           // distance 4
        u64 lo = umin64(m[k], m[k + 4]), hi = umax64(m[k], m[k + 4]);
        m[k] = lo; m[k + 4] = hi;
    }
#pragma unroll
    for (int base = 0; base < 8; base += 4)  // distance 2
#pragma unroll
        for (int k = 0; k < 2; ++k) {
            u64 lo = umin64(m[base + k], m[base + k + 2]);
            u64 hi = umax64(m[base + k], m[base + k + 2]);
            m[base + k] = lo; m[base + k + 2] = hi;
        }
#pragma unroll
    for (int base = 0; base < 8; base += 2) { // distance 1
        u64 lo = umin64(m[base], m[base + 1]), hi = umax64(m[base], m[base + 1]);
        m[base] = lo; m[base + 1] = hi;
    }
#pragma unroll
    for (int k = 0; k < 8; ++k) a[k] = m[k];
}

// ---------- 1a) kNN binning: 16x16 grid per batch -> global scratch ----------
__global__ __launch_bounds__(256) void knn_bin_kernel(const float* __restrict__ inputs,
                                                      float2* __restrict__ gsxy,
                                                      u16* __restrict__ gsid,
                                                      int* __restrict__ gcst) {
    __shared__ float px[Ss], py[Ss];
    __shared__ int hist[256];
    __shared__ int cur[256];
    int b = blockIdx.x;
    int tid = threadIdx.x;
    const float* base = inputs + (size_t)b * Ss * 2;
    for (int t = tid; t < Ss; t += 256) { px[t] = base[2 * t]; py[t] = base[2 * t + 1]; }
    hist[tid] = 0;
    __syncthreads();
    for (int t = tid; t < Ss; t += 256) {
        int cx = min(15, (int)(px[t] * 16.0f));
        int cy = min(15, (int)(py[t] * 16.0f));
        atomicAdd(&hist[cy * 16 + cx], 1);
    }
    __syncthreads();
    int cnt = hist[tid];
    for (int s = 1; s < 256; s <<= 1) {
        int u = (tid >= s) ? hist[tid - s] : 0;
        __syncthreads();
        hist[tid] += u;
        __syncthreads();
    }
    int st = hist[tid] - cnt;                // exclusive start
    cur[tid] = st;
    gcst[b * 260 + tid] = st;
    if (tid == 0) gcst[b * 260 + 256] = Ss;
    __syncthreads();
    for (int t = tid; t < Ss; t += 256) {
        float x = px[t], y = py[t];
        int cx = min(15, (int)(x * 16.0f));
        int cy = min(15, (int)(y * 16.0f));
        int p = atomicAdd(&cur[cy * 16 + cx], 1);
        gsxy[b * 1000 + p] = make_float2(x, y);
        gsid[b * 1000 + p] = (u16)t;
    }
}

// ---------- 1b) kNN query: 8-lane cooperative windowed scan ----------
__global__ __launch_bounds__(256) void knn_query_kernel(const float* __restrict__ inputs,
                                                        const float2* __restrict__ gsxy,
                                                        const u16* __restrict__ gsid,
                                                        const int* __restrict__ gcst,
                                                        u16* __restrict__ knn,
                                                        int* __restrict__ indeg) {
    __shared__ float2 sxy[Ss];
    __shared__ u16 sid[Ss];
    __shared__ int cst[257];
    int b = blockIdx.x;
    int tid = threadIdx.x;
    for (int t = tid; t < Ss; t += 256) { sxy[t] = gsxy[b * 1000 + t]; sid[t] = gsid[b * 1000 + t]; }
    for (int t = tid; t < 257; t += 256) cst[t] = gcst[b * 260 + t];
    __syncthreads();

    int sub = tid & 7;                   // lane within group
    int g = tid >> 3;                    // group 0..31
    int i = 2 + blockIdx.y * 32 + g;
    if (i >= Ss) return;

    float x = inputs[(size_t)b * 2000 + 2 * i];
    float y = inputs[(size_t)b * 2000 + 2 * i + 1];
    int cx = min(15, (int)(x * 16.0f));
    int cy = min(15, (int)(y * 16.0f));
    const float INF = __builtin_inff();
    constexpr float h = 0.0625f;

    u64 bd[8];
    int w = 1;
    for (;;) {
#pragma unroll
        for (int k = 0; k < 8; ++k) bd[k] = ~0ULL;
        int x0 = max(0, cx - w), x1 = min(15, cx + w);
        int y0 = max(0, cy - w), y1 = min(15, cy + w);
        for (int cyy = y0; cyy <= y1; ++cyy) {
            int p0 = cst[cyy * 16 + x0];
            int p1 = cst[cyy * 16 + x1 + 1];
            for (int p = p0 + sub; p < p1; p += 8) {
                float2 q = sxy[p];
                int j = sid[p];
                float dx = __fsub_rn(x, q.x);
                float dy = __fsub_rn(y, q.y);
                float d2 = __fadd_rn(__fmul_rn(dx, dx), __fmul_rn(dy, dy));
                float d = __fsqrt_rn(d2);
                u64 key = (((u64)__builtin_bit_cast(u32, d)) << 32) | (u32)j;
                key = (j == i) ? ~0ULL : key;
                ins8u(bd, key);
            }
        }
        merge8(bd, 1); merge8(bd, 2); merge8(bd, 4);   // group-wide 8 smallest
        float d7 = __builtin_bit_cast(float, (u32)(bd[6] >> 32));  // NaN if <7 found
        float bL = (x0 > 0)  ? (x - (float)x0 * h) : INF;
        float bR = (x1 < 15) ? ((float)(x1 + 1) * h - x) : INF;
        float bB = (y0 > 0)  ? (y - (float)y0 * h) : INF;
        float bT = (y1 < 15) ? ((float)(y1 + 1) * h - y) : INF;
        float bound = fminf(fminf(bL, bR), fminf(bB, bT));
        if (d7 <= bound - 2e-6f || w >= 16) break;     // NaN compare -> expand
        ++w;
    }

    if (sub == 0) {
        u16* kp = knn + ((size_t)b * NSRC + (i - 2)) * 7;
#pragma unroll
        for (int k = 0; k < 7; ++k) {
            int j = (int)(u32)bd[k];
            kp[k] = (u16)j;
            if (j >= 2) atomicAdd(&indeg[b * Ss + j], 1);
        }
    }
}

// ---------- 3) coalesced 3-phase scan (+ fused dinv) ----------
__global__ __launch_bounds__(1024) void scan1_kernel(const int* __restrict__ indeg,
                                                     int* __restrict__ offs,
                                                     int* __restrict__ bsum,
                                                     float* __restrict__ dinv) {
    __shared__ int sh[1024];
    int t = threadIdx.x;
    int idx = blockIdx.x * 1024 + t;
    int v = (idx < NN) ? indeg[idx] : 0;
    sh[t] = v;
    __syncthreads();
    for (int off = 1; off < 1024; off <<= 1) {
        int u = (t >= off) ? sh[t - off] : 0;
        __syncthreads();
        sh[t] += u;
        __syncthreads();
    }
    if (idx < NN) {
        offs[idx] = sh[t] - v;            // exclusive prefix
        int ii = idx % Ss;
        float deg = (ii == 0) ? 1.0f : (ii == 1) ? (float)(Ss - 1) : (float)(v + 2);
        dinv[idx] = 1.0f / __fsqrt_rn(deg);
    }
    if (t == 1023) bsum[blockIdx.x] = sh[1023];
}

__global__ void scan2_kernel(int* __restrict__ bsum) {
    if (threadIdx.x == 0) {
        int run = 0;
        for (int k = 0; k < 63; ++k) { int v = bsum[k]; bsum[k] = run; run += v; }
        bsum[63] = run;
    }
}

__global__ __launch_bounds__(1024) void scan3_kernel(int* __restrict__ offs,
                                                     const int* __restrict__ bsum) {
    int idx = blockIdx.x * 1024 + threadIdx.x;
    if (idx < NN) offs[idx] += bsum[blockIdx.x];
    if (idx == 0) offs[NN] = bsum[63];
}

// ---------- 4) scatter reverse adjacency ----------
__global__ __launch_bounds__(256) void fill_rev_kernel(const u16* __restrict__ knn,
                                                       const int* __restrict__ offs,
                                                       int* __restrict__ cursor,
                                                       u16* __restrict__ rev) {
    if (threadIdx.x >= 250) return;
    int b = blockIdx.x;
    int i = 2 + blockIdx.y * 250 + threadIdx.x;
    if (i >= Ss) return;
    const u16* kp = knn + ((size_t)b * NSRC + (i - 2)) * 7;
#pragma unroll
    for (int k = 0; k < 7; ++k) {
        int d = kp[k];
        if (d >= 2) {
            int n = b * Ss + d;
            int p = atomicAdd(&cursor[n], 1);
            rev[offs[n] + p] = (u16)i;
        }
    }
}

// ---------- 5) layer-0 weight folding ----------
__global__ __launch_bounds__(512) void fuse0_kernel(const float* __restrict__ Wc,
                                                    const float* __restrict__ bc,
                                                    const float* __restrict__ Ws,
                                                    const float* __restrict__ bs,
                                                    const float* __restrict__ W0,
                                                    float* __restrict__ A) {
    int h = threadIdx.x;
    float a0 = 0.f, a1 = 0.f, a2 = 0.f, a3 = 0.f;
    for (int c = 0; c < Dd; ++c) {
        float w = W0[c * Hh + h];
        a0 += Wc[c] * w;
        a1 += Wc[Dd + c] * w;
        a2 += Ws[c] * w;
        a3 += (bc[c] + bs[c]) * w;
    }
    A[h] = a0; A[Hh + h] = a1; A[2 * Hh + h] = a2; A[3 * Hh + h] = a3;
}

// ---------- 5b) layer-0 e-space aggregation (rank-4): ve[n] = agg(e)[n] ----------
__global__ __launch_bounds__(1024) void agg_e_kernel(const float* __restrict__ inputs,
                                                     const float* __restrict__ scor,
                                                     const float* __restrict__ dinv,
                                                     const int* __restrict__ offs,
                                                     const int* __restrict__ indeg,
                                                     const u16* __restrict__ rev,
                                                     float4* __restrict__ ve) {
    __shared__ float se0[Ss], se1[Ss], se2[Ss], sdv[Ss];
    __shared__ float4 depw[16];
    int b = blockIdx.x;
    int tid = threadIdx.x;
    int nb = b * Ss;
    const float* base = inputs + (size_t)nb * 2;
    for (int t = tid; t < Ss; t += 1024) {
        se0[t] = base[2 * t];
        se1[t] = base[2 * t + 1];
        se2[t] = scor[nb + t];
        sdv[t] = dinv[nb + t];
    }
    __syncthreads();

    // depot (node-1) sum: dep = sum_{r>=2} sdv[r] * e[r]
    float4 dep = {0.f, 0.f, 0.f, 0.f};
    for (int r = tid; r < Ss; r += 1024) {
        if (r >= 2) {
            float w = sdv[r];
            dep.x += se0[r] * w; dep.y += se1[r] * w;
            dep.z += se2[r] * w; dep.w += w;
        }
    }
#pragma unroll
    for (int m = 1; m < 64; m <<= 1) {
        dep.x += __shfl_xor(dep.x, m);
        dep.y += __shfl_xor(dep.y, m);
        dep.z += __shfl_xor(dep.z, m);
        dep.w += __shfl_xor(dep.w, m);
    }
    if ((tid & 63) == 0) depw[tid >> 6] = dep;
    __syncthreads();

    int i = tid;
    if (i >= Ss) return;
    float dn = sdv[i], sn = dn * dn;
    float4 acc = {0.f, 0.f, 0.f, 0.f};
    if (i >= 2) {
        int n = nb + i;
        int cnt = indeg[n], o = offs[n];
        float w0 = sdv[0];                 // == 1.0
        acc.x = se0[0] * w0; acc.y = se1[0] * w0;
        acc.z = se2[0] * w0; acc.w = w0;   // 0 -> i edge
        for (int e = 0; e < cnt; ++e) {
            int s = rev[o + e];
            float w = sdv[s];
            acc.x += se0[s] * w; acc.y += se1[s] * w;
            acc.z += se2[s] * w; acc.w += w;
        }
    } else if (i == 1) {
        float4 t = {0.f, 0.f, 0.f, 0.f};
#pragma unroll
        for (int k = 0; k < 16; ++k) {
            t.x += depw[k].x; t.y += depw[k].y;
            t.z += depw[k].z; t.w += depw[k].w;
        }
        acc = t;
    }
    float4 v;
    v.x = acc.x * dn + se0[i] * sn;
    v.y = acc.y * dn + se1[i] * sn;
    v.z = acc.z * dn + se2[i] * sn;
    v.w = acc.w * dn + sn;                 // e.w == 1
    ve[nb + i] = v;
}

// ---------- 5c) expand + sx partials: X[n,h]=relu(ve.A+b0); sxp[b][g][h] ----------
__global__ __launch_bounds__(256) void expand512p_kernel(const float4* __restrict__ ve,
                                                         const float* __restrict__ dinv,
                                                         const float* __restrict__ A,
                                                         const float* __restrict__ bias,
                                                         u16* __restrict__ X,
                                                         float* __restrict__ sxp) {
    __shared__ float4 sve[250];
    __shared__ float  sdv[250];
    __shared__ float  sred[8][256];
    int bx = blockIdx.x;               // 0..7
    int g = bx >> 1, cg = bx & 1;      // node-group 0..3, channel half 0..1
    int b = blockIdx.y;
    int n0 = g * 250;
    int nb = b * Ss;
    int tid = threadIdx.x;
    int c32 = tid & 31, slice = tid >> 5;     // 8 node-slices
    int ch = cg * 256 + c32 * 8;
    for (int t = tid; t < 250; t += 256) {
        sve[t] = ve[nb + n0 + t];
        sdv[t] = dinv[nb + n0 + t];
    }
    __syncthreads();

    float A0[8], A1[8], A2[8], A3[8], BZ[8];
#pragma unroll
    for (int j = 0; j < 8; ++j) {
        A0[j] = A[ch + j];
        A1[j] = A[Hh + ch + j];
        A2[j] = A[2 * Hh + ch + j];
        A3[j] = A[3 * Hh + ch + j];
        BZ[j] = bias[ch + j];
    }
    float acc[8] = {};
    for (int t = slice; t < 250; t += 8) {
        int n = n0 + t;
        float4 v = sve[t];
        float dw = (n >= 2) ? sdv[t] : 0.f;
        u32 ow[4];
#pragma unroll
        for (int j = 0; j < 4; ++j) {
            float z0 = fmaxf(v.x * A0[2 * j]     + v.y * A1[2 * j]     + v.z * A2[2 * j]     + v.w * A3[2 * j]     + BZ[2 * j],     0.f);
            float z1 = fmaxf(v.x * A0[2 * j + 1] + v.y * A1[2 * j + 1] + v.z * A2[2 * j + 1] + v.w * A3[2 * j + 1] + BZ[2 * j + 1], 0.f);
            u16 h0 = f2bf(z0), h1 = f2bf(z1);
            ow[j] = (u32)h0 | ((u32)h1 << 16);
            acc[2 * j]     += dw * bf2f(h0);
            acc[2 * j + 1] += dw * bf2f(h1);
        }
        uint4 o = {ow[0], ow[1], ow[2], ow[3]};
        *(uint4*)(X + (size_t)(nb + n) * Hh + ch) = o;
    }
#pragma unroll
    for (int j = 0; j < 8; ++j) sred[slice][c32 * 8 + j] = acc[j];
    __syncthreads();
    if (slice == 0) {
#pragma unroll
        for (int j = 0; j < 8; ++j) {
            float s = 0.f;
#pragma unroll
            for (int sl = 0; sl < 8; ++sl) s += sred[sl][c32 * 8 + j];
            sxp[((size_t)b * 4 + g) * Hh + ch + j] = s;
        }
    }
}

// ---------- 5d) k-split dep matmul: depp[kc][b][t] = sum_{k in chunk} sx[b][k]*W1[k][t] ----------
__global__ __launch_bounds__(512) void sxk_kernel(const float* __restrict__ sxp,
                                                  const float* __restrict__ W1,
                                                  float* __restrict__ depp) {
    __shared__ float sx[64];
    int kc = blockIdx.x;               // k-chunk 0..7
    int b  = blockIdx.y;
    int t  = threadIdx.x;
    if (t < 64) {
        int k = kc * 64 + t;
        float s = 0.f;
#pragma unroll
        for (int g = 0; g < 4; ++g) s += sxp[((size_t)b * 4 + g) * Hh + k];
        sx[t] = s;
    }
    __syncthreads();
    float a = 0.f;
#pragma unroll 8
    for (int kk = 0; kk < 64; ++kk)
        a += sx[kk] * W1[(size_t)(kc * 64 + kk) * Hh + t];
    depp[((size_t)kc * Bb + b) * Hh + t] = a;
}

// ---------- 5e) reduce 8 k-chunk partials -> flat depf[64][512] ----------
__global__ __launch_bounds__(512) void sxred_kernel(const float* __restrict__ depp,
                                                    float* __restrict__ depf) {
    int b = blockIdx.x, t = threadIdx.x;
    float s = 0.f;
#pragma unroll
    for (int kc = 0; kc < 8; ++kc)
        s += depp[((size_t)kc * Bb + b) * Hh + t];
    depf[(size_t)b * Hh + t] = s;
}

// ---------- 6) weight transpose -> single bf16 ----------
__global__ void transp_kernel(const float* __restrict__ src,
                              u16* __restrict__ dst, int R, int C) {
    int gid = blockIdx.x * 256 + threadIdx.x;
    if (gid >= R * C) return;
    int r = gid / C, c = gid - r * C;
    dst[c * R + r] = f2bf(src[gid]);
}

// ---------- 7) MFMA GEMM: Y(bf16) = A(bf16) @ W(bf16)^T ----------
__global__ __launch_bounds__(256) void gemm_kernel(const u16* __restrict__ A,
                                                   const u16* __restrict__ W,
                                                   u16* __restrict__ Y,
                                                   int K, int Ncols,
                                                   int nyb, int nxb) {
    __shared__ __align__(16) u16 lA[128][64];
    __shared__ __align__(16) u16 lW[128][64];

    int grp = blockIdx.x / (8 * nxb);
    int rem = blockIdx.x - grp * (8 * nxb);
    int xcd = rem & 7;
    int xb  = rem >> 3;
    int yb  = grp * 8 + xcd;
    if (yb >= nyb) return;

    int row0 = yb * 128;
    int col0 = xb * 128;
    int tid = threadIdx.x;
    int lane = tid & 63, wid = tid >> 6;
    int wm = (wid >> 1) * 64, wn = (wid & 1) * 64;
    int lanelo = lane & 15, quad = lane >> 4;

    int lrow = lane >> 3;               // row within 8-row chunk
    int lslot = lane & 7;               // 16B slot within row

    f32x4 acc[4][4] = {};

    for (int k0 = 0; k0 < K; k0 += 64) {
#pragma unroll
        for (int t = 0; t < 4; ++t) {
            int chunk = t * 4 + wid;                 // 0..15
            int row = chunk * 8 + lrow;              // 0..127
            int sc = lslot ^ (row & 7);              // pre-swizzled global slot
            gl_lds16(A + (size_t)(row0 + row) * K + k0 + sc * 8, &lA[chunk * 8][0]);
        }
#pragma unroll
        for (int t = 0; t < 4; ++t) {
            int chunk = t * 4 + wid;
            int row = chunk * 8 + lrow;
            int sc = lslot ^ (row & 7);
            gl_lds16(W + (size_t)(col0 + row) * K + k0 + sc * 8, &lW[chunk * 8][0]);
        }
        __syncthreads();

#pragma unroll
        for (int kk = 0; kk < 64; kk += 32) {
            short8 af[4], bw[4];
            int cbb = (kk >> 3) + quad;
#pragma unroll
            for (int mt = 0; mt < 4; ++mt) {
                int r = wm + mt * 16 + lanelo;
                af[mt] = *(const short8*)&lA[r][((cbb ^ (r & 7))) * 8];
            }
#pragma unroll
            for (int nt = 0; nt < 4; ++nt) {
                int r = wn + nt * 16 + lanelo;
                bw[nt] = *(const short8*)&lW[r][((cbb ^ (r & 7))) * 8];
            }
#pragma unroll
            for (int mt = 0; mt < 4; ++mt)
#pragma unroll
                for (int nt = 0; nt < 4; ++nt)
                    acc[mt][nt] = __builtin_amdgcn_mfma_f32_16x16x32_bf16(
                        af[mt], bw[nt], acc[mt][nt], 0, 0, 0);
        }
        __syncthreads();
    }

#pragma unroll
    for (int mt = 0; mt < 4; ++mt)
#pragma unroll
        for (int nt = 0; nt < 4; ++nt)
#pragma unroll
            for (int r = 0; r < 4; ++r) {
                int row = row0 + wm + mt * 16 + quad * 4 + r;
                int col = col0 + wn + nt * 16 + lanelo;
                Y[(size_t)row * Ncols + col] = f2bf(acc[mt][nt][r]);
            }
}

// ---------- 7b) depot-1 partial sums (layer 2 only) ----------
__global__ __launch_bounds__(1024) void dep1_kernel(const u16* __restrict__ y,
                                                    const float* __restrict__ dinv,
                                                    float* __restrict__ dq,
                                                    int M) {
    int b = blockIdx.x;
    int qq = blockIdx.y;                 // quarter 0..3
    int co = blockIdx.z * 128;
    int tid = threadIdx.x;
    int c4 = tid & 31;
    int es = tid >> 5;
    int j0 = 2 + qq * 250;
    int j1 = j0 + 250; if (j1 > Ss) j1 = Ss;
    const u16* yb = y + (size_t)b * Ss * M + co + c4 * 4;
    const float* dv = dinv + b * Ss;
    float a0 = 0.f, a1 = 0.f, a2 = 0.f, a3 = 0.f;
    for (int j = j0 + es; j < j1; j += 32) {
        float w = dv[j];
        float4 u = bf4(*(const ushort4*)(yb + (size_t)j * M));
        a0 += u.x * w; a1 += u.y * w; a2 += u.z * w; a3 += u.w * w;
    }
    __shared__ float4 red[1024];
    float4 mv; mv.x = a0; mv.y = a1; mv.z = a2; mv.w = a3;
    red[tid] = mv;
    __syncthreads();
#pragma unroll
    for (int s = 16; s > 0; s >>= 1) {
        if (es < s) {
            float4 o = red[tid + (s << 5)];
            float4 m = red[tid];
            m.x += o.x; m.y += o.y; m.z += o.z; m.w += o.w;
            red[tid] = m;
        }
        __syncthreads();
    }
    if (es == 0)
        *(float4*)(dq + ((size_t)qq * Bb + b) * M + co + c4 * 4) = red[c4];
}

// ---------- 8) wave-per-node aggregation M=512, XCD-pinned batch mapping ----------
__global__ __launch_bounds__(256) void aggw512_kernel(const u16* __restrict__ y,
                                                      const float* __restrict__ dinv,
                                                      const int* __restrict__ offs,
                                                      const int* __restrict__ indeg,
                                                      const u16* __restrict__ rev,
                                                      const float* __restrict__ bias,
                                                      const float* __restrict__ dep1,
                                                      u16* __restrict__ oX) {
    int tid = threadIdx.x;
    int wv = tid >> 6, lane = tid & 63;
    int bx = blockIdx.x;                  // 0..15999
    int b = (bx & 7) + 8 * (bx / 2000);   // batch, pinned per XCD
    int i = ((bx >> 3) % 250) * 4 + wv;   // node index within batch
    int nb = b * Ss;
    int n = nb + i;
    const u16* yB = y + (size_t)nb * 512 + lane * 8;

    float acc[8] = {};
    if (i >= 2) {
        int cnt = indeg[n], o = offs[n];
        int rv = 0; float rw = 0.f;
        if (lane < 16 && lane < cnt) { rv = rev[o + lane]; rw = dinv[nb + rv]; }
        float w0 = dinv[nb];              // == 1.0 (deg of node 0)
        uint4 v0 = *(const uint4*)yB;     // 0 -> i edge
        acc8(acc, v0, w0);
        int cl = cnt < 16 ? cnt : 16;
        int e = 0;
        for (; e + 4 <= cl; e += 4) {
            int   s0 = __shfl(rv, e),     s1 = __shfl(rv, e + 1);
            int   s2 = __shfl(rv, e + 2), s3 = __shfl(rv, e + 3);
            float w_0 = __shfl(rw, e),     w_1 = __shfl(rw, e + 1);
            float w_2 = __shfl(rw, e + 2), w_3 = __shfl(rw, e + 3);
            uint4 u0 = *(const uint4*)(yB + (size_t)s0 * 512);
            uint4 u1 = *(const uint4*)(yB + (size_t)s1 * 512);
            uint4 u2 = *(const uint4*)(yB + (size_t)s2 * 512);
            uint4 u3 = *(const uint4*)(yB + (size_t)s3 * 512);
            acc8(acc, u0, w_0); acc8(acc, u1, w_1);
            acc8(acc, u2, w_2); acc8(acc, u3, w_3);
        }
        for (; e < cl; ++e) {
            int s = __shfl(rv, e); float ww = __shfl(rw, e);
            uint4 u = *(const uint4*)(yB + (size_t)s * 512);
            acc8(acc, u, ww);
        }
        for (; e < cnt; ++e) {            // rare tail (indeg > 16)
            int s = rev[o + e]; float ww = dinv[nb + s];
            uint4 u = *(const uint4*)(yB + (size_t)s * 512);
            acc8(acc, u, ww);
        }
    } else if (i == 1) {
        const float* dp = dep1 + (size_t)b * 512 + lane * 8;
        float4 v0 = *(const float4*)dp;
        float4 v1 = *(const float4*)(dp + 4);
        acc[0] = v0.x; acc[1] = v0.y; acc[2] = v0.z; acc[3] = v0.w;
        acc[4] = v1.x; acc[5] = v1.y; acc[6] = v1.z; acc[7] = v1.w;
    }
    float dn = dinv[n], sn = dn * dn;
    float s8[8];
    unp8(s8, *(const uint4*)(yB + (size_t)i * 512));
    float4 bl = *(const float4*)(bias + lane * 8);
    float4 bh = *(const float4*)(bias + lane * 8 + 4);
    float bz[8] = {bl.x, bl.y, bl.z, bl.w, bh.x, bh.y, bh.z, bh.w};
    u32 ow[4];
#pragma unroll
    for (int k = 0; k < 4; ++k) {
        float z0 = acc[2 * k]     * dn + s8[2 * k]     * sn + bz[2 * k];
        float z1 = acc[2 * k + 1] * dn + s8[2 * k + 1] * sn + bz[2 * k + 1];
        ow[k] = (u32)f2bf(fmaxf(z0, 0.f)) | ((u32)f2bf(fmaxf(z1, 0.f)) << 16);
    }
    uint4 ov = {ow[0], ow[1], ow[2], ow[3]};
    *(uint4*)(oX + (size_t)n * 512 + lane * 8) = ov;
}

// ---------- 9) wave-per-node final aggregation M=128, fp32 out ----------
__global__ __launch_bounds__(256) void aggwf128_kernel(const u16* __restrict__ y,
                                                       const float* __restrict__ dinv,
                                                       const int* __restrict__ offs,
                                                       const int* __restrict__ indeg,
                                                       const u16* __restrict__ rev,
                                                       const float* __restrict__ bias,
                                                       const float* __restrict__ dep1,
                                                       float* __restrict__ out) {
    int tid = threadIdx.x;
    int wv = tid >> 6, lane = tid & 63;
    int bx = blockIdx.x;                  // 0..15999
    int b = (bx & 7) + 8 * (bx / 2000);   // batch, pinned per XCD
    int i = ((bx >> 3) % 250) * 4 + wv;   // node index within batch
    int nb = b * Ss;
    int n = nb + i;
    const u16* yB = y + (size_t)nb * 128 + lane * 2;

    float acc[2] = {};
    if (i >= 2) {
        int cnt = indeg[n], o = offs[n];
        int rv = 0; float rw = 0.f;
        if (lane < 16 && lane < cnt) { rv = rev[o + lane]; rw = dinv[nb + rv]; }
        float w0 = dinv[nb];              // == 1.0
        acc2(acc, *(const u32*)yB, w0);   // 0 -> i edge
        int cl = cnt < 16 ? cnt : 16;
        int e = 0;
        for (; e + 4 <= cl; e += 4) {
            int   s0 = __shfl(rv, e),     s1 = __shfl(rv, e + 1);
            int   s2 = __shfl(rv, e + 2), s3 = __shfl(rv, e + 3);
            float w_0 = __shfl(rw, e),     w_1 = __shfl(rw, e + 1);
            float w_2 = __shfl(rw, e + 2), w_3 = __shfl(rw, e + 3);
            u32 u0 = *(const u32*)(yB + (size_t)s0 * 128);
            u32 u1 = *(const u32*)(yB + (size_t)s1 * 128);
            u32 u2 = *(const u32*)(yB + (size_t)s2 * 128);
            u32 u3 = *(const u32*)(yB + (size_t)s3 * 128);
            acc2(acc, u0, w_0); acc2(acc, u1, w_1);
            acc2(acc, u2, w_2); acc2(acc, u3, w_3);
        }
        for (; e < cl; ++e) {
            int s = __shfl(rv, e); float ww = __shfl(rw, e);
            acc2(acc, *(const u32*)(yB + (size_t)s * 128), ww);
        }
        for (; e < cnt; ++e) {            // rare tail (indeg > 16)
            int s = rev[o + e]; float ww = dinv[nb + s];
            acc2(acc, *(const u32*)(yB + (size_t)s * 128), ww);
        }
    } else if (i == 1) {
        const float* dp = dep1 + (size_t)b * 128 + lane * 2;
#pragma unroll
        for (int qq = 0; qq < 4; ++qq) {
            float2 v = *(const float2*)(dp + (size_t)qq * Bb * 128);
            acc[0] += v.x; acc[1] += v.y;
        }
    }
    float dn = dinv[n], sn = dn * dn;
    u32 sv = *(const u32*)(yB + (size_t)i * 128);
    float s0 = __builtin_bit_cast(float, sv << 16);
    float s1 = __builtin_bit_cast(float, sv & 0xFFFF0000u);
    float2 bz = *(const float2*)(bias + lane * 2);
    float2 z;
    z.x = acc[0] * dn + s0 * sn + bz.x;
    z.y = acc[1] * dn + s1 * sn + bz.y;
    *(float2*)(out + (size_t)n * 128 + lane * 2) = z;
}

// ---------- workspace layout (bytes) ----------
constexpr size_t O_INDEG  = 0;                       // 256000
constexpr size_t O_CURSOR = 256000;                  // 256000
constexpr size_t O_OFFS   = 512000;                  // 256016
constexpr size_t O_DINV   = 768256;                  // 256000
constexpr size_t O_KNN    = 1024256;                 // 893824
constexpr size_t O_REV    = 1918080;                 // 893824
constexpr size_t O_AMAT   = 2811904;                 // 8192
constexpr size_t O_WT1    = 2942976;                 // 524288
constexpr size_t O_WT2    = 3467264;                 // 131072
constexpr size_t O_X      = 3598336;                 // 65536000 (bf16 acts)
constexpr size_t O_Y      = 69134336;                // 65536000 (bf16 y; ve fp32 early)
constexpr size_t O_SXP    = 134670336;               // 64*4*512*4 = 524288 (sx partials)
constexpr size_t O_DEPF   = 135194624;               // 64*512*4 = 131072 (flat dep L1;
                                                     //  aliased by L2 quarters later)
constexpr size_t O_BSUM   = 135325696;               // 256
// kNN scratch aliased into O_X (consumed before expand writes xbf):
constexpr size_t O_GSXY   = O_X;                     // 64*1000*8 = 512000
constexpr size_t O_GSID   = O_X + 512000;            // 64*1000*2 = 128000
constexpr size_t O_GCST   = O_X + 640000;            // 64*260*4 = 66560
// ve (64000 float4 = 1.024 MB) aliased into O_Y (consumed before gemm1 writes ybf)
constexpr size_t O_VE     = O_Y;
// depp (8*64*512*4 = 1 MB) aliased into O_Y+4MB (live only sxk->sxred, pre-gemm1)
constexpr size_t O_DEPP   = O_Y + 4194304;

extern "C" void kernel_launch(void* const* d_in, const int* in_sizes, int n_in,
                              void* d_out, int out_size, void* d_ws, size_t ws_size,
                              hipStream_t stream) {
    const float* inputs = (const float*)d_in[0];
    const float* scor   = (const float*)d_in[1];
    const float* Wc     = (const float*)d_in[2];
    const float* bc     = (const float*)d_in[3];
    const float* Ws     = (const float*)d_in[4];
    const float* bs     = (const float*)d_in[5];
    const float* W0     = (const float*)d_in[6];
    const float* b0     = (const float*)d_in[7];
    const float* W1     = (const float*)d_in[8];
    const float* b1     = (const float*)d_in[9];
    const float* W2     = (const float*)d_in[10];
    const float* b2     = (const float*)d_in[11];

    char* w = (char*)d_ws;
    int*    indeg  = (int*)(w + O_INDEG);
    int*    cursor = (int*)(w + O_CURSOR);
    int*    offs   = (int*)(w + O_OFFS);
    float*  dinv   = (float*)(w + O_DINV);
    u16*    knn    = (u16*)(w + O_KNN);
    u16*    rev    = (u16*)(w + O_REV);
    float*  amat   = (float*)(w + O_AMAT);
    u16*    wt1    = (u16*)(w + O_WT1);
    u16*    wt2    = (u16*)(w + O_WT2);
    u16*    xbf    = (u16*)(w + O_X);
    u16*    ybf    = (u16*)(w + O_Y);
    float*  sxp    = (float*)(w + O_SXP);
    float*  depf   = (float*)(w + O_DEPF);
    float*  depp   = (float*)(w + O_DEPP);
    int*    bsum   = (int*)(w + O_BSUM);
    float2* gsxy   = (float2*)(w + O_GSXY);
    u16*    gsid   = (u16*)(w + O_GSID);
    int*    gcst   = (int*)(w + O_GCST);
    float4* ve     = (float4*)(w + O_VE);

    hipMemsetAsync(w + O_INDEG, 0, 512000, stream);  // indeg + cursor

    knn_bin_kernel<<<Bb, 256, 0, stream>>>(inputs, gsxy, gsid, gcst);
    knn_query_kernel<<<dim3(Bb, 32), 256, 0, stream>>>(inputs, gsxy, gsid, gcst, knn, indeg);
    scan1_kernel<<<63, 1024, 0, stream>>>(indeg, offs, bsum, dinv);
    scan2_kernel<<<1, 64, 0, stream>>>(bsum);
    scan3_kernel<<<63, 1024, 0, stream>>>(offs, bsum);
    fill_rev_kernel<<<dim3(Bb, 4), 256, 0, stream>>>(knn, offs, cursor, rev);

    fuse0_kernel<<<1, 512, 0, stream>>>(Wc, bc, Ws, bs, W0, amat);
    transp_kernel<<<(Hh * Hh + 255) / 256, 256, 0, stream>>>(W1, wt1, Hh, Hh);
    transp_kernel<<<(Hh * Dd + 255) / 256, 256, 0, stream>>>(W2, wt2, Hh, Dd);

    // layer 0: rank-4 e-space aggregation + fused expand with sx partials
    agg_e_kernel<<<Bb, 1024, 0, stream>>>(inputs, scor, dinv, offs, indeg, rev, ve);
    expand512p_kernel<<<dim3(8, Bb), 256, 0, stream>>>(ve, dinv, amat, b0, xbf, sxp);
    sxk_kernel<<<dim3(8, Bb), 512, 0, stream>>>(sxp, W1, depp);    // k-split dep matmul
    sxred_kernel<<<Bb, 512, 0, stream>>>(depp, depf);              // -> flat dep1a
    // layer 1: [N,512] @ [512,512]
    gemm_kernel<<<63 * 32, 256, 0, stream>>>(xbf, wt1, ybf, Hh, Hh, 500, 4);
    aggw512_kernel<<<NN / 4, 256, 0, stream>>>(ybf, dinv, offs, indeg, rev, b1, depf, xbf);
    // layer 2: [N,512] @ [512,128]
    gemm_kernel<<<63 * 8, 256, 0, stream>>>(xbf, wt2, ybf, Hh, Dd, 500, 1);
    dep1_kernel<<<dim3(Bb, 4, 1), 1024, 0, stream>>>(ybf, dinv, depf, Dd);   // quarters, aliased
    aggwf128_kernel<<<NN / 4, 256, 0, stream>>>(ybf, dinv, offs, indeg, rev, b2, depf, (float*)d_out);
}